// Round 1
// baseline (22.336 us; speedup 1.0000x reference)
//
#include <hip/hip_runtime.h>
#include <math.h>

#define D 2
#define HID 64
#define WIDTH 64
#define CONDDIM 4
#define BATCH 262144
#define BLK 128  // WIDTH*D

static __device__ __forceinline__ float fexp2(float x){ return __builtin_amdgcn_exp2f(x); }
static __device__ __forceinline__ float frcp(float x){ return __builtin_amdgcn_rcpf(x); }

// ---------------- Kernel 1: hypernetwork (t -> per-block params) ----------------
// params layout (floats):
//   [8w+0] = W0*2log2e   [8w+1] = W1*2log2e   [8w+2] = Bb*2log2e
//   [8w+3] = WUs = W0*U0/64 + W1*U1/64  (raw W, gated U)
//   [8w+4] = U0/64       [8w+5] = U1/64      [8w+6..7] = pad
//   [512]  = sum_w WUs
__global__ __launch_bounds__(448) void hyper_kernel(
    const float* __restrict__ t,
    const float* __restrict__ w1, const float* __restrict__ b1,
    const float* __restrict__ w2, const float* __restrict__ b2,
    const float* __restrict__ w3, const float* __restrict__ b3,
    float* __restrict__ params)
{
    __shared__ float p1s[HID];
    __shared__ float p2s[HID];
    __shared__ float p3s[3*BLK + WIDTH];
    const int tid = threadIdx.x;

    if (tid < HID) p1s[tid] = tanhf(t[0]*w1[tid] + b1[tid]);
    __syncthreads();

    if (tid < HID) {
        float acc = b2[tid];
        const float* row = w2 + tid*HID;
        #pragma unroll 8
        for (int k = 0; k < HID; ++k) acc = fmaf(p1s[k], row[k], acc);
        p2s[tid] = tanhf(acc);
    }
    __syncthreads();

    {   // 448 rows of w3, one per thread
        float a0=0.f, a1=0.f, a2=0.f, a3=0.f;
        const float* row = w3 + tid*HID;
        #pragma unroll 4
        for (int k = 0; k < HID; k += 4) {
            a0 = fmaf(p2s[k+0], row[k+0], a0);
            a1 = fmaf(p2s[k+1], row[k+1], a1);
            a2 = fmaf(p2s[k+2], row[k+2], a2);
            a3 = fmaf(p2s[k+3], row[k+3], a3);
        }
        p3s[tid] = b3[tid] + ((a0+a1)+(a2+a3));
    }
    __syncthreads();

    if (tid < WIDTH) {
        const int w = tid;
        const float C = 2.885390081777927f; // 2*log2(e)
        float W0 = p3s[2*w],        W1 = p3s[2*w+1];
        float U0 = p3s[BLK+2*w],    U1 = p3s[BLK+2*w+1];
        float G0 = p3s[2*BLK+2*w],  G1 = p3s[2*BLK+2*w+1];
        float Bb = p3s[3*BLK+w];
        U0 *= 1.0f/(1.0f + expf(-G0));
        U1 *= 1.0f/(1.0f + expf(-G1));
        float Us0 = U0 * (1.0f/WIDTH);
        float Us1 = U1 * (1.0f/WIDTH);
        float WUs = W0*Us0 + W1*Us1;
        params[8*w+0] = W0*C;
        params[8*w+1] = W1*C;
        params[8*w+2] = Bb*C;
        params[8*w+3] = WUs;
        params[8*w+4] = Us0;
        params[8*w+5] = Us1;
        params[8*w+6] = 0.0f;
        params[8*w+7] = 0.0f;
        float s = WUs;
        #pragma unroll
        for (int off = 32; off > 0; off >>= 1) s += __shfl_down(s, off);
        if (w == 0) params[512] = s;
    }
}

// ---------------- Kernel 2: batch ODE func (2 elements per thread) ----------------
__global__ __launch_bounds__(256) void ode_kernel(
    const float4* __restrict__ z4,     // [B/2] : {z0A,z1A,z0B,z1B}
    const float4* __restrict__ c4,     // [B]   : condition rows
    const float* __restrict__ cl_wz, const float* __restrict__ cl_bz,
    const float* __restrict__ cl_wc, const float* __restrict__ cl_bc,
    const float* __restrict__ params,
    float* __restrict__ out)
{
    const int gid = blockIdx.x * 256 + threadIdx.x;
    const float L2E = 1.4426950408889634f;
    const float C2  = 2.885390081777927f;   // 2*log2(e)

    // small uniform weights (uniform addresses -> scalar loads)
    float wz[8], wc[16], bb[4];
    #pragma unroll
    for (int j = 0; j < 8;  ++j) wz[j] = cl_wz[j];
    #pragma unroll
    for (int j = 0; j < 16; ++j) wc[j] = cl_wc[j];
    #pragma unroll
    for (int j = 0; j < 4;  ++j) bb[j] = cl_bz[j] + cl_bc[j];

    float4 zz = z4[gid];
    float4 cA = c4[2*gid];
    float4 cB = c4[2*gid+1];

    float a[4], b[4];
    #pragma unroll
    for (int j = 0; j < 4; ++j) {
        float ta = fmaf(zz.x, wz[2*j], fmaf(zz.y, wz[2*j+1], bb[j]));
        ta = fmaf(cA.x, wc[4*j], ta); ta = fmaf(cA.y, wc[4*j+1], ta);
        ta = fmaf(cA.z, wc[4*j+2], ta); ta = fmaf(cA.w, wc[4*j+3], ta);
        a[j] = ta;
        float tb = fmaf(zz.z, wz[2*j], fmaf(zz.w, wz[2*j+1], bb[j]));
        tb = fmaf(cB.x, wc[4*j], tb); tb = fmaf(cB.y, wc[4*j+1], tb);
        tb = fmaf(cB.z, wc[4*j+2], tb); tb = fmaf(cB.w, wc[4*j+3], tb);
        b[j] = tb;
    }
    // zc = tanh(a[0:2]) * sigmoid(a[2:4])
    float zc0A = fmaf(-2.0f, frcp(1.0f + fexp2(a[0]*C2)), 1.0f) * frcp(1.0f + fexp2(-a[2]*L2E));
    float zc1A = fmaf(-2.0f, frcp(1.0f + fexp2(a[1]*C2)), 1.0f) * frcp(1.0f + fexp2(-a[3]*L2E));
    float zc0B = fmaf(-2.0f, frcp(1.0f + fexp2(b[0]*C2)), 1.0f) * frcp(1.0f + fexp2(-b[2]*L2E));
    float zc1B = fmaf(-2.0f, frcp(1.0f + fexp2(b[1]*C2)), 1.0f) * frcp(1.0f + fexp2(-b[3]*L2E));

    const float4* __restrict__ P = (const float4*)params;
    float acc0A=0.f, acc1A=0.f, trA=0.f;
    float acc0B=0.f, acc1B=0.f, trB=0.f;
    #pragma unroll 8
    for (int w = 0; w < WIDTH; ++w) {
        float4 pa = P[2*w];     // {W0*C2, W1*C2, Bb*C2, WUs}
        float4 pb = P[2*w+1];   // {Us0, Us1, -, -}
        float preA = fmaf(pa.x, zc0A, fmaf(pa.y, zc1A, pa.z));
        float preB = fmaf(pa.x, zc0B, fmaf(pa.y, zc1B, pa.z));
        float hA = fmaf(-2.0f, frcp(1.0f + fexp2(preA)), 1.0f);
        float hB = fmaf(-2.0f, frcp(1.0f + fexp2(preB)), 1.0f);
        acc0A = fmaf(hA, pb.x, acc0A);  acc1A = fmaf(hA, pb.y, acc1A);
        acc0B = fmaf(hB, pb.x, acc0B);  acc1B = fmaf(hB, pb.y, acc1B);
        trA = fmaf(hA*hA, pa.w, trA);
        trB = fmaf(hB*hB, pa.w, trB);
    }
    float sWU = params[512];

    ((float4*)out)[gid] = make_float4(acc0A, acc1A, acc0B, acc1B);           // dz_dt
    ((float2*)(out + 2*(size_t)BATCH))[gid] = make_float2(trA - sWU, trB - sWU); // dlogp
    float4* oc = (float4*)(out + 3*(size_t)BATCH);
    oc[2*gid]   = cA;                                                         // condition copy
    oc[2*gid+1] = cB;
}

extern "C" void kernel_launch(void* const* d_in, const int* in_sizes, int n_in,
                              void* d_out, int out_size, void* d_ws, size_t ws_size,
                              hipStream_t stream) {
    const float* t         = (const float*)d_in[0];
    const float* z         = (const float*)d_in[1];
    // d_in[2] = logp_z (unused by the reference outputs)
    const float* condition = (const float*)d_in[3];
    const float* hn_w1 = (const float*)d_in[4];
    const float* hn_b1 = (const float*)d_in[5];
    const float* hn_w2 = (const float*)d_in[6];
    const float* hn_b2 = (const float*)d_in[7];
    const float* hn_w3 = (const float*)d_in[8];
    const float* hn_b3 = (const float*)d_in[9];
    const float* cl_wz = (const float*)d_in[10];
    const float* cl_bz = (const float*)d_in[11];
    const float* cl_wc = (const float*)d_in[12];
    const float* cl_bc = (const float*)d_in[13];

    float* params = (float*)d_ws;   // needs 513 floats

    hyper_kernel<<<1, 448, 0, stream>>>(t, hn_w1, hn_b1, hn_w2, hn_b2, hn_w3, hn_b3, params);

    const int nthreads = BATCH / 2;           // 2 elements per thread
    const int block = 256;
    const int grid = nthreads / block;        // 512 blocks
    ode_kernel<<<grid, block, 0, stream>>>((const float4*)z, (const float4*)condition,
                                           cl_wz, cl_bz, cl_wc, cl_bc, params, (float*)d_out);
}

// Round 2
// 20.840 us; speedup vs baseline: 1.0718x; 1.0718x over previous
//
#include <hip/hip_runtime.h>
#include <math.h>

#define D 2
#define HID 64
#define WIDTH 64
#define CONDDIM 4
#define BATCH 262144
#define BLK 128  // WIDTH*D

static __device__ __forceinline__ float fexp2(float x){ return __builtin_amdgcn_exp2f(x); }
static __device__ __forceinline__ float frcp(float x){ return __builtin_amdgcn_rcpf(x); }

// One fused kernel: every block redundantly computes the hypernetwork
// (t -> 513 params) into LDS (~32 KFLOP + 130 KB L2-resident weight reads),
// then runs the batch phase (2 elements/thread) reading params via
// uniform-address LDS broadcast reads.
//
// LDS params layout (floats, 32B stride per w):
//   ps[8w+0] = W0*2log2e   ps[8w+1] = W1*2log2e   ps[8w+2] = Bb*2log2e
//   ps[8w+3] = WUs = (W0*U0 + W1*U1)/64  (raw W, gated U)
//   ps[8w+4] = U0/64       ps[8w+5] = U1/64       ps[8w+6..7] = pad
//   ps[512]  = sum_w WUs
__global__ __launch_bounds__(256) void fused_ode_kernel(
    const float* __restrict__ t,
    const float* __restrict__ hw1, const float* __restrict__ hb1,
    const float* __restrict__ hw2, const float* __restrict__ hb2,
    const float* __restrict__ hw3, const float* __restrict__ hb3,
    const float4* __restrict__ z4,     // [B/2] : {z0A,z1A,z0B,z1B}
    const float4* __restrict__ c4,     // [B]   : condition rows
    const float* __restrict__ cl_wz, const float* __restrict__ cl_bz,
    const float* __restrict__ cl_wc, const float* __restrict__ cl_bc,
    float* __restrict__ out)
{
    __shared__ float p1s[HID];
    __shared__ float p2s[HID];
    __shared__ float p3s[3*BLK + WIDTH];
    __shared__ __align__(16) float ps[520];

    const int tid = threadIdx.x;
    const int gid = blockIdx.x * 256 + tid;
    const float L2E = 1.4426950408889634f;
    const float C2  = 2.885390081777927f;   // 2*log2(e)

    // ---- issue batch loads early; HBM latency hides under the hypernet ----
    float4 zz = z4[gid];
    float4 cA = c4[2*gid];
    float4 cB = c4[2*gid+1];

    // small uniform weights (uniform addresses -> scalar loads)
    float wz[8], wc[16], bb[4];
    #pragma unroll
    for (int j = 0; j < 8;  ++j) wz[j] = cl_wz[j];
    #pragma unroll
    for (int j = 0; j < 16; ++j) wc[j] = cl_wc[j];
    #pragma unroll
    for (int j = 0; j < 4;  ++j) bb[j] = cl_bz[j] + cl_bc[j];

    // ---------------- hypernet phase (per-block redundant) ----------------
    if (tid < HID) p1s[tid] = tanhf(t[0]*hw1[tid] + hb1[tid]);
    __syncthreads();

    if (tid < HID) {
        float a0=0.f, a1=0.f, a2=0.f, a3=0.f;
        const float4* row = (const float4*)(hw2 + tid*HID);
        #pragma unroll 4
        for (int k = 0; k < HID/4; ++k) {
            float4 r = row[k];
            a0 = fmaf(p1s[4*k+0], r.x, a0);
            a1 = fmaf(p1s[4*k+1], r.y, a1);
            a2 = fmaf(p1s[4*k+2], r.z, a2);
            a3 = fmaf(p1s[4*k+3], r.w, a3);
        }
        p2s[tid] = tanhf(hb2[tid] + ((a0+a1)+(a2+a3)));
    }
    __syncthreads();

    {   // 448 rows of w3: rows tid and 256+tid (tid<192)
        int r = tid;
        {
            float a0=0.f, a1=0.f, a2=0.f, a3=0.f;
            const float4* row = (const float4*)(hw3 + r*HID);
            #pragma unroll 4
            for (int k = 0; k < HID/4; ++k) {
                float4 rv = row[k];
                a0 = fmaf(p2s[4*k+0], rv.x, a0);
                a1 = fmaf(p2s[4*k+1], rv.y, a1);
                a2 = fmaf(p2s[4*k+2], rv.z, a2);
                a3 = fmaf(p2s[4*k+3], rv.w, a3);
            }
            p3s[r] = hb3[r] + ((a0+a1)+(a2+a3));
        }
        if (tid < 192) {
            int r2 = 256 + tid;
            float a0=0.f, a1=0.f, a2=0.f, a3=0.f;
            const float4* row = (const float4*)(hw3 + r2*HID);
            #pragma unroll 4
            for (int k = 0; k < HID/4; ++k) {
                float4 rv = row[k];
                a0 = fmaf(p2s[4*k+0], rv.x, a0);
                a1 = fmaf(p2s[4*k+1], rv.y, a1);
                a2 = fmaf(p2s[4*k+2], rv.z, a2);
                a3 = fmaf(p2s[4*k+3], rv.w, a3);
            }
            p3s[r2] = hb3[r2] + ((a0+a1)+(a2+a3));
        }
    }
    __syncthreads();

    if (tid < WIDTH) {   // exactly wave 0
        const int w = tid;
        float W0 = p3s[2*w],        W1 = p3s[2*w+1];
        float U0 = p3s[BLK+2*w],    U1 = p3s[BLK+2*w+1];
        float G0 = p3s[2*BLK+2*w],  G1 = p3s[2*BLK+2*w+1];
        float Bb = p3s[3*BLK+w];
        U0 *= frcp(1.0f + fexp2(-G0*L2E));
        U1 *= frcp(1.0f + fexp2(-G1*L2E));
        float Us0 = U0 * (1.0f/WIDTH);
        float Us1 = U1 * (1.0f/WIDTH);
        float WUs = W0*Us0 + W1*Us1;
        ps[8*w+0] = W0*C2;
        ps[8*w+1] = W1*C2;
        ps[8*w+2] = Bb*C2;
        ps[8*w+3] = WUs;
        ps[8*w+4] = Us0;
        ps[8*w+5] = Us1;
        ps[8*w+6] = 0.0f;
        ps[8*w+7] = 0.0f;
        float s = WUs;
        #pragma unroll
        for (int off = 32; off > 0; off >>= 1) s += __shfl_down(s, off);
        if (w == 0) ps[512] = s;
    }
    __syncthreads();

    // ---------------- batch phase ----------------
    float a[4], b[4];
    #pragma unroll
    for (int j = 0; j < 4; ++j) {
        float ta = fmaf(zz.x, wz[2*j], fmaf(zz.y, wz[2*j+1], bb[j]));
        ta = fmaf(cA.x, wc[4*j], ta); ta = fmaf(cA.y, wc[4*j+1], ta);
        ta = fmaf(cA.z, wc[4*j+2], ta); ta = fmaf(cA.w, wc[4*j+3], ta);
        a[j] = ta;
        float tb = fmaf(zz.z, wz[2*j], fmaf(zz.w, wz[2*j+1], bb[j]));
        tb = fmaf(cB.x, wc[4*j], tb); tb = fmaf(cB.y, wc[4*j+1], tb);
        tb = fmaf(cB.z, wc[4*j+2], tb); tb = fmaf(cB.w, wc[4*j+3], tb);
        b[j] = tb;
    }
    // zc = tanh(a[0:2]) * sigmoid(a[2:4])
    float zc0A = fmaf(-2.0f, frcp(1.0f + fexp2(a[0]*C2)), 1.0f) * frcp(1.0f + fexp2(-a[2]*L2E));
    float zc1A = fmaf(-2.0f, frcp(1.0f + fexp2(a[1]*C2)), 1.0f) * frcp(1.0f + fexp2(-a[3]*L2E));
    float zc0B = fmaf(-2.0f, frcp(1.0f + fexp2(b[0]*C2)), 1.0f) * frcp(1.0f + fexp2(-b[2]*L2E));
    float zc1B = fmaf(-2.0f, frcp(1.0f + fexp2(b[1]*C2)), 1.0f) * frcp(1.0f + fexp2(-b[3]*L2E));

    // condition copy out (fire-and-forget stores before the compute loop)
    float4* oc = (float4*)(out + 3*(size_t)BATCH);
    oc[2*gid]   = cA;
    oc[2*gid+1] = cB;

    const float4* __restrict__ P = (const float4*)ps;  // LDS broadcast reads
    float acc0A=0.f, acc1A=0.f, trA=0.f;
    float acc0B=0.f, acc1B=0.f, trB=0.f;
    #pragma unroll 8
    for (int w = 0; w < WIDTH; ++w) {
        float4 pa = P[2*w];     // {W0*C2, W1*C2, Bb*C2, WUs}
        float4 pb = P[2*w+1];   // {Us0, Us1, -, -}
        float preA = fmaf(pa.x, zc0A, fmaf(pa.y, zc1A, pa.z));
        float preB = fmaf(pa.x, zc0B, fmaf(pa.y, zc1B, pa.z));
        float hA = fmaf(-2.0f, frcp(1.0f + fexp2(preA)), 1.0f);
        float hB = fmaf(-2.0f, frcp(1.0f + fexp2(preB)), 1.0f);
        acc0A = fmaf(hA, pb.x, acc0A);  acc1A = fmaf(hA, pb.y, acc1A);
        acc0B = fmaf(hB, pb.x, acc0B);  acc1B = fmaf(hB, pb.y, acc1B);
        trA = fmaf(hA*hA, pa.w, trA);
        trB = fmaf(hB*hB, pa.w, trB);
    }
    float sWU = ps[512];

    ((float4*)out)[gid] = make_float4(acc0A, acc1A, acc0B, acc1B);              // dz_dt
    ((float2*)(out + 2*(size_t)BATCH))[gid] = make_float2(trA - sWU, trB - sWU); // dlogp
}

extern "C" void kernel_launch(void* const* d_in, const int* in_sizes, int n_in,
                              void* d_out, int out_size, void* d_ws, size_t ws_size,
                              hipStream_t stream) {
    const float* t         = (const float*)d_in[0];
    const float* z         = (const float*)d_in[1];
    // d_in[2] = logp_z (unused by the reference outputs)
    const float* condition = (const float*)d_in[3];
    const float* hn_w1 = (const float*)d_in[4];
    const float* hn_b1 = (const float*)d_in[5];
    const float* hn_w2 = (const float*)d_in[6];
    const float* hn_b2 = (const float*)d_in[7];
    const float* hn_w3 = (const float*)d_in[8];
    const float* hn_b3 = (const float*)d_in[9];
    const float* cl_wz = (const float*)d_in[10];
    const float* cl_bz = (const float*)d_in[11];
    const float* cl_wc = (const float*)d_in[12];
    const float* cl_bc = (const float*)d_in[13];

    const int nthreads = BATCH / 2;           // 2 elements per thread
    const int block = 256;
    const int grid = nthreads / block;        // 512 blocks
    fused_ode_kernel<<<grid, block, 0, stream>>>(
        t, hn_w1, hn_b1, hn_w2, hn_b2, hn_w3, hn_b3,
        (const float4*)z, (const float4*)condition,
        cl_wz, cl_bz, cl_wc, cl_bc, (float*)d_out);
}